// Round 1
// baseline (439.172 us; speedup 1.0000x reference)
//
#include <hip/hip_runtime.h>
#include <cstdint>
#include <cstddef>

#define DEV static __device__ __forceinline__

typedef __bf16 v8bf __attribute__((ext_vector_type(8)));
typedef float v4f __attribute__((ext_vector_type(4)));

DEV unsigned short f2bf(float f) {
    unsigned int u = __float_as_uint(f);
    u = (u + 0x7fffu + ((u >> 16) & 1u)) >> 16;
    return (unsigned short)u;
}

DEV float siluf(float x) { return x / (1.f + __expf(-x)); }
DEV float softplusf(float x) { return log1pf(__expf(-fabsf(x))) + fmaxf(x, 0.f); }

// ---------------- cast kernels ----------------
__global__ __launch_bounds__(256) void cast_f32_bf16(const float* __restrict__ in,
                                                     unsigned short* __restrict__ out, int n) {
    int i = (blockIdx.x * 256 + threadIdx.x) * 4;
    if (i + 3 < n) {
        float4 v = *reinterpret_cast<const float4*>(in + i);
        ushort4 o;
        o.x = f2bf(v.x); o.y = f2bf(v.y); o.z = f2bf(v.z); o.w = f2bf(v.w);
        *reinterpret_cast<ushort4*>(out + i) = o;
    } else {
        for (; i < n; i++) out[i] = f2bf(in[i]);
    }
}

// cast first 64 of 96 columns of x_dbl to bf16 (dt GEMM input)
__global__ __launch_bounds__(256) void cast_xdbl64(const float* __restrict__ xdbl,
                                                   unsigned short* __restrict__ out) {
    int i = blockIdx.x * 256 + threadIdx.x;   // over 4096*64
    int r = i >> 6, c = i & 63;
    out[i] = f2bf(xdbl[(size_t)r * 96 + c]);
}

__global__ __launch_bounds__(256) void aneg_kernel(const float* __restrict__ alog,
                                                   float* __restrict__ an, int n) {
    int i = blockIdx.x * 256 + threadIdx.x;
    if (i < n) an[i] = -__expf(alog[i]);
}

// ---------------- LayerNorm -> bf16 ----------------
__global__ __launch_bounds__(256) void ln_kernel(const float* __restrict__ x,
                                                 const float* __restrict__ g,
                                                 const float* __restrict__ bt,
                                                 unsigned short* __restrict__ out) {
    int row = blockIdx.x;                      // 4096 rows, 1024 cols
    const float* xr = x + (size_t)row * 1024;
    float4 v = reinterpret_cast<const float4*>(xr)[threadIdx.x];
    float s  = v.x + v.y + v.z + v.w;
    float s2 = v.x * v.x + v.y * v.y + v.z * v.z + v.w * v.w;
    #pragma unroll
    for (int o = 32; o > 0; o >>= 1) { s += __shfl_down(s, o); s2 += __shfl_down(s2, o); }
    __shared__ float red[8];
    int w = threadIdx.x >> 6;
    if ((threadIdx.x & 63) == 0) { red[w] = s; red[4 + w] = s2; }
    __syncthreads();
    if (threadIdx.x == 0) {
        float a = red[0] + red[1] + red[2] + red[3];
        float b = red[4] + red[5] + red[6] + red[7];
        red[0] = a * (1.f / 1024.f);
        red[4] = b * (1.f / 1024.f);
    }
    __syncthreads();
    float mu = red[0];
    float rstd = rsqrtf(red[4] - mu * mu + 1e-5f);
    float4 gg = reinterpret_cast<const float4*>(g)[threadIdx.x];
    float4 bb = reinterpret_cast<const float4*>(bt)[threadIdx.x];
    ushort4 o;
    o.x = f2bf((v.x - mu) * rstd * gg.x + bb.x);
    o.y = f2bf((v.y - mu) * rstd * gg.y + bb.y);
    o.z = f2bf((v.z - mu) * rstd * gg.z + bb.z);
    o.w = f2bf((v.w - mu) * rstd * gg.w + bb.w);
    reinterpret_cast<ushort4*>(out + (size_t)row * 1024)[threadIdx.x] = o;
}

// ---------------- causal depthwise conv + silu ----------------
// xz: (B, L, 2048) token-major; x = first 1024 cols. Branch-time t; REV maps to orig pos.
template <int REV>
__global__ __launch_bounds__(256) void conv_silu(const float* __restrict__ xz,
                                                 const float* __restrict__ cw,
                                                 const float* __restrict__ cb,
                                                 float* __restrict__ u,
                                                 unsigned short* __restrict__ ubf) {
    int idx = blockIdx.x * 256 + threadIdx.x;  // over B*L*1024
    int d = idx & 1023;
    int t = (idx >> 10) & 1023;
    int b = idx >> 20;
    float acc = cb[d];
    #pragma unroll
    for (int k = 0; k < 4; k++) {
        int s = t - 3 + k;
        if (s >= 0) {
            int p = REV ? (1023 - s) : s;
            acc = fmaf(cw[(d << 2) + k], xz[(((size_t)b * 1024 + p) << 11) + d], acc);
        }
    }
    float val = siluf(acc);
    u[idx] = val;
    ubf[idx] = f2bf(val);
}

// ---------------- selective scan, chunked (CS=32, NC=32) ----------------
__global__ __launch_bounds__(256) void scan_p1(const float* __restrict__ delta,
                                               const float* __restrict__ u,
                                               const float* __restrict__ xdbl,
                                               const float* __restrict__ Aneg,
                                               float* __restrict__ hfin,
                                               float* __restrict__ aprod) {
    __shared__ float BC[32 * 32];
    int tid = threadIdx.x;
    int dblk = blockIdx.x & 3;
    int chunk = (blockIdx.x >> 2) & 31;
    int b = blockIdx.x >> 7;
    int d = (dblk << 8) + tid;
    int t0 = chunk << 5;
    for (int i = tid; i < 32 * 32; i += 256)
        BC[i] = xdbl[((size_t)b * 1024 + t0 + (i >> 5)) * 96 + 64 + (i & 31)];
    __syncthreads();
    float A[16], h[16], ap[16];
    #pragma unroll
    for (int n = 0; n < 16; n++) { A[n] = Aneg[(d << 4) + n]; h[n] = 0.f; ap[n] = 1.f; }
    for (int j = 0; j < 32; j++) {
        int t = t0 + j;
        size_t off = ((size_t)b * 1024 + t) * 1024 + d;
        float dl = delta[off];
        float ut = u[off];
        float du = dl * ut;
        #pragma unroll
        for (int n = 0; n < 16; n++) {
            float a = __expf(dl * A[n]);
            ap[n] *= a;
            h[n] = fmaf(h[n], a, du * BC[(j << 5) + n]);
        }
    }
    size_t base = (((size_t)b * 1024 + d) * 32 + chunk) * 16;
    #pragma unroll
    for (int n = 0; n < 16; n++) { hfin[base + n] = h[n]; aprod[base + n] = ap[n]; }
}

__global__ __launch_bounds__(256) void scan_p2(const float* __restrict__ hfin,
                                               const float* __restrict__ aprod,
                                               float* __restrict__ hin) {
    int idx = blockIdx.x * 256 + threadIdx.x;  // 65536 = (b*1024+d)*16 + n
    int n = idx & 15;
    size_t bd = idx >> 4;
    size_t base = (bd << 9) + n;               // bd*32*16 + n
    float h = 0.f;
    for (int c = 0; c < 32; c++) {
        size_t o = base + ((size_t)c << 4);
        hin[o] = h;
        h = fmaf(aprod[o], h, hfin[o]);
    }
}

template <int REV, int ACC>
__global__ __launch_bounds__(256) void scan_p3(const float* __restrict__ delta,
                                               const float* __restrict__ u,
                                               const float* __restrict__ xdbl,
                                               const float* __restrict__ Aneg,
                                               const float* __restrict__ hin,
                                               const float* __restrict__ Dp,
                                               const float* __restrict__ xz,
                                               const float* __restrict__ yprev,
                                               float* __restrict__ yf32,
                                               unsigned short* __restrict__ ybf) {
    __shared__ float BC[32 * 32];
    int tid = threadIdx.x;
    int dblk = blockIdx.x & 3;
    int chunk = (blockIdx.x >> 2) & 31;
    int b = blockIdx.x >> 7;
    int d = (dblk << 8) + tid;
    int t0 = chunk << 5;
    for (int i = tid; i < 32 * 32; i += 256)
        BC[i] = xdbl[((size_t)b * 1024 + t0 + (i >> 5)) * 96 + 64 + (i & 31)];
    __syncthreads();
    float A[16], h[16];
    size_t hbase = (((size_t)b * 1024 + d) * 32 + chunk) * 16;
    #pragma unroll
    for (int n = 0; n < 16; n++) { A[n] = Aneg[(d << 4) + n]; h[n] = hin[hbase + n]; }
    float Dd = Dp[d];
    for (int j = 0; j < 32; j++) {
        int t = t0 + j;
        size_t off = ((size_t)b * 1024 + t) * 1024 + d;
        float dl = delta[off];
        float ut = u[off];
        float du = dl * ut;
        float y = 0.f;
        #pragma unroll
        for (int n = 0; n < 16; n++) {
            float a = __expf(dl * A[n]);
            h[n] = fmaf(h[n], a, du * BC[(j << 5) + n]);
            y = fmaf(h[n], BC[(j << 5) + 16 + n], y);
        }
        y = fmaf(Dd, ut, y);
        int p = REV ? (1023 - t) : t;
        size_t po = ((size_t)b * 1024 + p) * 1024 + d;
        float z = xz[(((size_t)b * 1024 + p) << 11) + 1024 + d];
        float val = y * siluf(z);
        if (ACC) ybf[po] = f2bf(yprev[po] + val);
        else     yf32[po] = val;
    }
}

// ---------------- bf16 MFMA GEMM: C[m,n] = sum_k A[m,k]*B[n,k] ----------------
// EPI: 0 = store fp32, 1 = store bf16, 2 = softplus(c + bias[n]) fp32, 3 = c + bias[n] + res fp32
template <int EPI>
__global__ __launch_bounds__(256) void gemm_bt(const unsigned short* __restrict__ A,
                                               const unsigned short* __restrict__ B,
                                               int M, int N, int K,
                                               const float* __restrict__ bias,
                                               const float* __restrict__ res,
                                               float* __restrict__ Cf,
                                               unsigned short* __restrict__ Cb) {
    __shared__ unsigned short As[64][40];
    __shared__ unsigned short Bs[64][40];
    int tid = threadIdx.x;
    int bm = blockIdx.x, bn = blockIdx.y;
    int row = tid >> 2, cg = (tid & 3) << 3;
    int lane = tid & 63, w = tid >> 6;
    int wm = w >> 1, wn = w & 1;
    int l15 = lane & 15, kq = (lane >> 4) << 3;

    v4f acc00 = {0.f, 0.f, 0.f, 0.f};
    v4f acc01 = acc00, acc10 = acc00, acc11 = acc00;

    const size_t arow = (size_t)(bm * 64 + row) * K;
    int brow_i = bn * 64 + row;
    const size_t brow = (size_t)brow_i * K;
    bool bok = brow_i < N;

    for (int k0 = 0; k0 < K; k0 += 32) {
        float4 av = *reinterpret_cast<const float4*>(A + arow + k0 + cg);
        float4 bv = make_float4(0.f, 0.f, 0.f, 0.f);
        if (bok) bv = *reinterpret_cast<const float4*>(B + brow + k0 + cg);
        __syncthreads();
        *reinterpret_cast<float4*>(&As[row][cg]) = av;
        *reinterpret_cast<float4*>(&Bs[row][cg]) = bv;
        __syncthreads();
        v8bf a0 = *reinterpret_cast<const v8bf*>(&As[(wm << 5) + l15][kq]);
        v8bf a1 = *reinterpret_cast<const v8bf*>(&As[(wm << 5) + 16 + l15][kq]);
        v8bf b0 = *reinterpret_cast<const v8bf*>(&Bs[(wn << 5) + l15][kq]);
        v8bf b1 = *reinterpret_cast<const v8bf*>(&Bs[(wn << 5) + 16 + l15][kq]);
        acc00 = __builtin_amdgcn_mfma_f32_16x16x32_bf16(a0, b0, acc00, 0, 0, 0);
        acc01 = __builtin_amdgcn_mfma_f32_16x16x32_bf16(a0, b1, acc01, 0, 0, 0);
        acc10 = __builtin_amdgcn_mfma_f32_16x16x32_bf16(a1, b0, acc10, 0, 0, 0);
        acc11 = __builtin_amdgcn_mfma_f32_16x16x32_bf16(a1, b1, acc11, 0, 0, 0);
    }

    int mbase = bm * 64 + (wm << 5);
    int nbase = bn * 64 + (wn << 5) + l15;
    int rbase = (lane >> 4) << 2;
    v4f accs[4] = {acc00, acc01, acc10, acc11};
    #pragma unroll
    for (int mi = 0; mi < 2; mi++) {
        #pragma unroll
        for (int ni = 0; ni < 2; ni++) {
            int n = nbase + ni * 16;
            if (n >= N) continue;
            v4f ac = accs[mi * 2 + ni];
            #pragma unroll
            for (int r = 0; r < 4; r++) {
                int m = mbase + mi * 16 + rbase + r;
                size_t o = (size_t)m * N + n;
                float c = ac[r];
                if (EPI == 0)      Cf[o] = c;
                else if (EPI == 1) Cb[o] = f2bf(c);
                else if (EPI == 2) Cf[o] = softplusf(c + bias[n]);
                else               Cf[o] = c + bias[n] + res[o];
            }
        }
    }
}

// ---------------- host launch ----------------
extern "C" void kernel_launch(void* const* d_in, const int* in_sizes, int n_in,
                              void* d_out, int out_size, void* d_ws, size_t ws_size,
                              hipStream_t stream) {
    (void)in_sizes; (void)n_in; (void)out_size; (void)ws_size;
    const int TOK = 4096;           // B*L
    const int DM = 1024, DI = 1024;

    const float* hs       = (const float*)d_in[0];
    const float* ln_g     = (const float*)d_in[1];
    const float* ln_b     = (const float*)d_in[2];
    const float* in_proj  = (const float*)d_in[3];
    const float* conv_w   = (const float*)d_in[4];
    const float* conv_b   = (const float*)d_in[5];
    const float* x_proj   = (const float*)d_in[6];
    const float* dt_proj  = (const float*)d_in[7];
    const float* dt_b     = (const float*)d_in[8];
    const float* A_log    = (const float*)d_in[9];
    const float* Dp       = (const float*)d_in[10];
    const float* conv_w_b = (const float*)d_in[11];
    const float* conv_b_b = (const float*)d_in[12];
    const float* x_proj_b = (const float*)d_in[13];
    const float* dt_proj_b= (const float*)d_in[14];
    const float* dt_b_b   = (const float*)d_in[15];
    const float* A_log_b  = (const float*)d_in[16];
    const float* Dp_b     = (const float*)d_in[17];
    const float* out_proj = (const float*)d_in[18];
    const float* fc_w     = (const float*)d_in[19];
    const float* fc_b     = (const float*)d_in[20];

    uint8_t* p = (uint8_t*)d_ws;
    auto alloc = [&](size_t bytes) -> void* {
        void* r = (void*)p;
        p += (bytes + 255) & ~(size_t)255;
        return r;
    };
    unsigned short* hsb   = (unsigned short*)alloc((size_t)TOK * DM * 2);
    float*          xz    = (float*)alloc((size_t)TOK * 2048 * 4);
    float*          u     = (float*)alloc((size_t)TOK * DI * 4);
    unsigned short* ubf   = (unsigned short*)alloc((size_t)TOK * DI * 2);
    float*          xdbl  = (float*)alloc((size_t)TOK * 96 * 4);
    unsigned short* xdA   = (unsigned short*)alloc((size_t)TOK * 64 * 2);
    float*          delta = (float*)alloc((size_t)TOK * DI * 4);
    float*          hfin  = (float*)alloc((size_t)4 * 1024 * 32 * 16 * 4);
    float*          aprod = (float*)alloc((size_t)4 * 1024 * 32 * 16 * 4);
    float*          hin   = (float*)alloc((size_t)4 * 1024 * 32 * 16 * 4);
    float*          yf    = (float*)alloc((size_t)TOK * DI * 4);
    unsigned short* ybf   = (unsigned short*)alloc((size_t)TOK * DI * 2);
    unsigned short* o1b   = (unsigned short*)alloc((size_t)TOK * DI * 2);
    unsigned short* wip   = (unsigned short*)alloc((size_t)2048 * 1024 * 2);
    unsigned short* wxp   = (unsigned short*)alloc((size_t)96 * 1024 * 2);
    unsigned short* wxpB  = (unsigned short*)alloc((size_t)96 * 1024 * 2);
    unsigned short* wdt   = (unsigned short*)alloc((size_t)1024 * 64 * 2);
    unsigned short* wdtB  = (unsigned short*)alloc((size_t)1024 * 64 * 2);
    unsigned short* wout  = (unsigned short*)alloc((size_t)1024 * 1024 * 2);
    unsigned short* wfc   = (unsigned short*)alloc((size_t)1024 * 1024 * 2);
    float*          AnF   = (float*)alloc((size_t)DI * 16 * 4);
    float*          AnB   = (float*)alloc((size_t)DI * 16 * 4);

    auto castN = [&](const float* src, unsigned short* dst, int n) {
        cast_f32_bf16<<<(n / 4 + 255) / 256, 256, 0, stream>>>(src, dst, n);
    };
    castN(in_proj,  wip,  2048 * 1024);
    castN(x_proj,   wxp,  96 * 1024);
    castN(x_proj_b, wxpB, 96 * 1024);
    castN(dt_proj,  wdt,  1024 * 64);
    castN(dt_proj_b,wdtB, 1024 * 64);
    castN(out_proj, wout, 1024 * 1024);
    castN(fc_w,     wfc,  1024 * 1024);
    aneg_kernel<<<64, 256, 0, stream>>>(A_log,   AnF, 16384);
    aneg_kernel<<<64, 256, 0, stream>>>(A_log_b, AnB, 16384);

    ln_kernel<<<TOK, 256, 0, stream>>>(hs, ln_g, ln_b, hsb);

    // xz = hs @ in_proj.T : (4096, 2048)
    gemm_bt<0><<<dim3(64, 32), 256, 0, stream>>>(hsb, wip, TOK, 2048, 1024,
                                                 nullptr, nullptr, xz, nullptr);
    // ---- forward branch ----
    conv_silu<0><<<16384, 256, 0, stream>>>(xz, conv_w, conv_b, u, ubf);
    gemm_bt<0><<<dim3(64, 2), 256, 0, stream>>>(ubf, wxp, TOK, 96, 1024,
                                                nullptr, nullptr, xdbl, nullptr);
    cast_xdbl64<<<1024, 256, 0, stream>>>(xdbl, xdA);
    gemm_bt<2><<<dim3(64, 16), 256, 0, stream>>>(xdA, wdt, TOK, 1024, 64,
                                                 dt_b, nullptr, delta, nullptr);
    scan_p1<<<512, 256, 0, stream>>>(delta, u, xdbl, AnF, hfin, aprod);
    scan_p2<<<256, 256, 0, stream>>>(hfin, aprod, hin);
    scan_p3<0, 0><<<512, 256, 0, stream>>>(delta, u, xdbl, AnF, hin, Dp, xz,
                                           nullptr, yf, nullptr);
    // ---- backward branch ----
    conv_silu<1><<<16384, 256, 0, stream>>>(xz, conv_w_b, conv_b_b, u, ubf);
    gemm_bt<0><<<dim3(64, 2), 256, 0, stream>>>(ubf, wxpB, TOK, 96, 1024,
                                                nullptr, nullptr, xdbl, nullptr);
    cast_xdbl64<<<1024, 256, 0, stream>>>(xdbl, xdA);
    gemm_bt<2><<<dim3(64, 16), 256, 0, stream>>>(xdA, wdtB, TOK, 1024, 64,
                                                 dt_b_b, nullptr, delta, nullptr);
    scan_p1<<<512, 256, 0, stream>>>(delta, u, xdbl, AnB, hfin, aprod);
    scan_p2<<<256, 256, 0, stream>>>(hfin, aprod, hin);
    scan_p3<1, 1><<<512, 256, 0, stream>>>(delta, u, xdbl, AnB, hin, Dp_b, xz,
                                           yf, nullptr, ybf);
    // ---- head ----
    gemm_bt<1><<<dim3(64, 16), 256, 0, stream>>>(ybf, wout, TOK, 1024, 1024,
                                                 nullptr, nullptr, nullptr, o1b);
    gemm_bt<3><<<dim3(64, 16), 256, 0, stream>>>(o1b, wfc, TOK, 1024, 1024,
                                                 fc_b, hs, (float*)d_out, nullptr);
}

// Round 2
// 433.125 us; speedup vs baseline: 1.0140x; 1.0140x over previous
//
#include <hip/hip_runtime.h>
#include <cstdint>
#include <cstddef>

#define DEV static __device__ __forceinline__

typedef __bf16 bf16t;
typedef bf16t v8bf __attribute__((ext_vector_type(8)));
typedef float v4f __attribute__((ext_vector_type(4)));

DEV unsigned short f2bf(float f) {
    unsigned int u = __float_as_uint(f);
    u = (u + 0x7fffu + ((u >> 16) & 1u)) >> 16;
    return (unsigned short)u;
}
DEV float bf2f(unsigned short s) { return __uint_as_float((unsigned int)s << 16); }
DEV float siluf(float x) { return x / (1.f + __expf(-x)); }
DEV float softplusf(float x) { return log1pf(__expf(-fabsf(x))) + fmaxf(x, 0.f); }

DEV void gld16(const void* g, void* l) {
    __builtin_amdgcn_global_load_lds((const __attribute__((address_space(1))) void*)g,
                                     (__attribute__((address_space(3))) void*)l, 16, 0, 0);
}

// ---------------- fused weight casts ----------------
struct CastSeg { const float* src; unsigned short* dst; int blk0; };
struct CastJobs { CastSeg seg[7]; };

__global__ __launch_bounds__(256) void cast_multi(CastJobs jobs) {
    int b = blockIdx.x;
    int s = 0;
    #pragma unroll
    for (int i = 1; i < 7; i++) if (b >= jobs.seg[i].blk0) s = i;
    const float* src = jobs.seg[s].src;
    unsigned short* dst = jobs.seg[s].dst;
    int i = (b - jobs.seg[s].blk0) * 1024 + threadIdx.x * 4;   // all seg sizes %1024==0
    float4 v = *reinterpret_cast<const float4*>(src + i);
    ushort4 o;
    o.x = f2bf(v.x); o.y = f2bf(v.y); o.z = f2bf(v.z); o.w = f2bf(v.w);
    *reinterpret_cast<ushort4*>(dst + i) = o;
}

// both A_log -> -exp
__global__ __launch_bounds__(256) void aneg2(const float* __restrict__ a,
                                             const float* __restrict__ b,
                                             float* __restrict__ oa,
                                             float* __restrict__ ob) {
    int i = blockIdx.x * 256 + threadIdx.x;   // 16384 each
    oa[i] = -__expf(a[i]);
    ob[i] = -__expf(b[i]);
}

// cast first 64 of 96 columns of x_dbl to bf16 (dt GEMM input)
__global__ __launch_bounds__(256) void cast_xdbl64(const float* __restrict__ xdbl,
                                                   unsigned short* __restrict__ out) {
    int i = blockIdx.x * 256 + threadIdx.x;   // over 4096*64
    int r = i >> 6, c = i & 63;
    out[i] = f2bf(xdbl[(size_t)r * 96 + c]);
}

// ---------------- LayerNorm -> bf16 ----------------
__global__ __launch_bounds__(256) void ln_kernel(const float* __restrict__ x,
                                                 const float* __restrict__ g,
                                                 const float* __restrict__ bt,
                                                 unsigned short* __restrict__ out) {
    int row = blockIdx.x;
    const float* xr = x + (size_t)row * 1024;
    float4 v = reinterpret_cast<const float4*>(xr)[threadIdx.x];
    float s  = v.x + v.y + v.z + v.w;
    float s2 = v.x * v.x + v.y * v.y + v.z * v.z + v.w * v.w;
    #pragma unroll
    for (int o = 32; o > 0; o >>= 1) { s += __shfl_down(s, o); s2 += __shfl_down(s2, o); }
    __shared__ float red[8];
    int w = threadIdx.x >> 6;
    if ((threadIdx.x & 63) == 0) { red[w] = s; red[4 + w] = s2; }
    __syncthreads();
    if (threadIdx.x == 0) {
        float a = red[0] + red[1] + red[2] + red[3];
        float b = red[4] + red[5] + red[6] + red[7];
        red[0] = a * (1.f / 1024.f);
        red[4] = b * (1.f / 1024.f);
    }
    __syncthreads();
    float mu = red[0];
    float rstd = rsqrtf(red[4] - mu * mu + 1e-5f);
    float4 gg = reinterpret_cast<const float4*>(g)[threadIdx.x];
    float4 bb = reinterpret_cast<const float4*>(bt)[threadIdx.x];
    ushort4 o;
    o.x = f2bf((v.x - mu) * rstd * gg.x + bb.x);
    o.y = f2bf((v.y - mu) * rstd * gg.y + bb.y);
    o.z = f2bf((v.z - mu) * rstd * gg.z + bb.z);
    o.w = f2bf((v.w - mu) * rstd * gg.w + bb.w);
    reinterpret_cast<ushort4*>(out + (size_t)row * 1024)[threadIdx.x] = o;
}

// ---------------- causal depthwise conv + silu -> bf16 ----------------
template <int REV>
__global__ __launch_bounds__(256) void conv_silu(const float* __restrict__ xz,
                                                 const float* __restrict__ cw,
                                                 const float* __restrict__ cb,
                                                 unsigned short* __restrict__ ubf) {
    int idx = blockIdx.x * 256 + threadIdx.x;  // over B*L*1024
    int d = idx & 1023;
    int t = (idx >> 10) & 1023;
    int b = idx >> 20;
    float acc = cb[d];
    #pragma unroll
    for (int k = 0; k < 4; k++) {
        int s = t - 3 + k;
        if (s >= 0) {
            int p = REV ? (1023 - s) : s;
            acc = fmaf(cw[(d << 2) + k], xz[(((size_t)b * 1024 + p) << 11) + d], acc);
        }
    }
    ubf[idx] = f2bf(siluf(acc));
}

// ---------------- selective scan, chunked (CS=32, NC=32) ----------------
__global__ __launch_bounds__(256) void scan_p1(const float* __restrict__ delta,
                                               const unsigned short* __restrict__ ubf,
                                               const float* __restrict__ xdbl,
                                               const float* __restrict__ Aneg,
                                               float* __restrict__ hfin,
                                               float* __restrict__ aprod) {
    __shared__ float BC[32 * 32];
    int tid = threadIdx.x;
    int dblk = blockIdx.x & 3;
    int chunk = (blockIdx.x >> 2) & 31;
    int b = blockIdx.x >> 7;
    int d = (dblk << 8) + tid;
    int t0 = chunk << 5;
    for (int i = tid; i < 32 * 32; i += 256)
        BC[i] = xdbl[((size_t)b * 1024 + t0 + (i >> 5)) * 96 + 64 + (i & 31)];
    __syncthreads();
    float A[16], h[16], ap[16];
    #pragma unroll
    for (int n = 0; n < 16; n++) { A[n] = Aneg[(d << 4) + n]; h[n] = 0.f; ap[n] = 1.f; }
    for (int j = 0; j < 32; j++) {
        int t = t0 + j;
        size_t off = ((size_t)b * 1024 + t) * 1024 + d;
        float dl = delta[off];
        float ut = bf2f(ubf[off]);
        float du = dl * ut;
        #pragma unroll
        for (int n = 0; n < 16; n++) {
            float a = __expf(dl * A[n]);
            ap[n] *= a;
            h[n] = fmaf(h[n], a, du * BC[(j << 5) + n]);
        }
    }
    size_t base = (((size_t)b * 1024 + d) * 32 + chunk) * 16;
    #pragma unroll
    for (int n = 0; n < 16; n++) { hfin[base + n] = h[n]; aprod[base + n] = ap[n]; }
}

__global__ __launch_bounds__(256) void scan_p2(const float* __restrict__ hfin,
                                               const float* __restrict__ aprod,
                                               float* __restrict__ hin) {
    int idx = blockIdx.x * 256 + threadIdx.x;  // 65536 = (b*1024+d)*16 + n
    int n = idx & 15;
    size_t bd = idx >> 4;
    size_t base = (bd << 9) + n;
    float h = 0.f;
    for (int c = 0; c < 32; c++) {
        size_t o = base + ((size_t)c << 4);
        hin[o] = h;
        h = fmaf(aprod[o], h, hfin[o]);
    }
}

template <int REV, int ACC>
__global__ __launch_bounds__(256) void scan_p3(const float* __restrict__ delta,
                                               const unsigned short* __restrict__ ubf,
                                               const float* __restrict__ xdbl,
                                               const float* __restrict__ Aneg,
                                               const float* __restrict__ hin,
                                               const float* __restrict__ Dp,
                                               const float* __restrict__ xz,
                                               const float* __restrict__ yprev,
                                               float* __restrict__ yf32,
                                               unsigned short* __restrict__ ybf) {
    __shared__ float BC[32 * 32];
    int tid = threadIdx.x;
    int dblk = blockIdx.x & 3;
    int chunk = (blockIdx.x >> 2) & 31;
    int b = blockIdx.x >> 7;
    int d = (dblk << 8) + tid;
    int t0 = chunk << 5;
    for (int i = tid; i < 32 * 32; i += 256)
        BC[i] = xdbl[((size_t)b * 1024 + t0 + (i >> 5)) * 96 + 64 + (i & 31)];
    __syncthreads();
    float A[16], h[16];
    size_t hbase = (((size_t)b * 1024 + d) * 32 + chunk) * 16;
    #pragma unroll
    for (int n = 0; n < 16; n++) { A[n] = Aneg[(d << 4) + n]; h[n] = hin[hbase + n]; }
    float Dd = Dp[d];
    for (int j = 0; j < 32; j++) {
        int t = t0 + j;
        size_t off = ((size_t)b * 1024 + t) * 1024 + d;
        float dl = delta[off];
        float ut = bf2f(ubf[off]);
        float du = dl * ut;
        float y = 0.f;
        #pragma unroll
        for (int n = 0; n < 16; n++) {
            float a = __expf(dl * A[n]);
            h[n] = fmaf(h[n], a, du * BC[(j << 5) + n]);
            y = fmaf(h[n], BC[(j << 5) + 16 + n], y);
        }
        y = fmaf(Dd, ut, y);
        int p = REV ? (1023 - t) : t;
        size_t po = ((size_t)b * 1024 + p) * 1024 + d;
        float z = xz[(((size_t)b * 1024 + p) << 11) + 1024 + d];
        float val = y * siluf(z);
        if (ACC) ybf[po] = f2bf(yprev[po] + val);
        else     yf32[po] = val;
    }
}

// ---------------- 128x128 MFMA GEMM (m97 structure): C = A * B^T ----------------
// requires M%128==0, N%128==0, K%32==0
// EPI: 0 = fp32 store, 1 = bf16 store, 2 = softplus(c+bias[n]) fp32, 3 = c+bias[n]+res fp32
template <int EPI>
__global__ __launch_bounds__(256) void gemm128(const unsigned short* __restrict__ A,
                                               const unsigned short* __restrict__ B,
                                               int M, int N, int K,
                                               const float* __restrict__ bias,
                                               const float* __restrict__ res,
                                               float* __restrict__ Cf,
                                               unsigned short* __restrict__ Cb) {
    __shared__ unsigned short As[128 * 32];
    __shared__ unsigned short Bs[128 * 32];
    const int tid = threadIdx.x;
    const int lane = tid & 63, w = tid >> 6;      // 4 waves
    const int wm = w >> 1, wn = w & 1;            // 2x2 wave grid, 64x64 per wave
    const int l15 = lane & 15, kq = (lane >> 4) << 3;
    const int bm = blockIdx.x, bn = blockIdx.y;

    // staging: wave w loads rows [w*32, w*32+32) of the 128-row tile, 2 instrs of 16 rows
    const int sr = lane >> 2;                 // row within 16-row group
    const int sc = (lane & 3) << 3;           // k-col element offset 0/8/16/24
    const size_t aB0 = (size_t)(bm * 128 + w * 32 + sr) * K + sc;
    const size_t bB0 = (size_t)(bn * 128 + w * 32 + sr) * K + sc;
    unsigned short* lA0 = &As[(w * 32) * 32];
    unsigned short* lA1 = &As[(w * 32 + 16) * 32];
    unsigned short* lB0 = &Bs[(w * 32) * 32];
    unsigned short* lB1 = &Bs[(w * 32 + 16) * 32];

    v4f acc[4][4];
    #pragma unroll
    for (int i = 0; i < 4; i++)
        #pragma unroll
        for (int j = 0; j < 4; j++) acc[i][j] = v4f{0.f, 0.f, 0.f, 0.f};

    for (int k0 = 0; k0 < K; k0 += 32) {
        __syncthreads();
        gld16(A + aB0 + k0, lA0);
        gld16(A + aB0 + (size_t)16 * K + k0, lA1);
        gld16(B + bB0 + k0, lB0);
        gld16(B + bB0 + (size_t)16 * K + k0, lB1);
        __syncthreads();
        v8bf af[4], bf[4];
        #pragma unroll
        for (int i = 0; i < 4; i++) {
            af[i] = *reinterpret_cast<const v8bf*>(&As[(wm * 64 + i * 16 + l15) * 32 + kq]);
            bf[i] = *reinterpret_cast<const v8bf*>(&Bs[(wn * 64 + i * 16 + l15) * 32 + kq]);
        }
        #pragma unroll
        for (int mi = 0; mi < 4; mi++)
            #pragma unroll
            for (int ni = 0; ni < 4; ni++)
                acc[mi][ni] = __builtin_amdgcn_mfma_f32_16x16x32_bf16(af[mi], bf[ni], acc[mi][ni], 0, 0, 0);
    }

    const int rbase = (lane >> 4) << 2;
    #pragma unroll
    for (int mi = 0; mi < 4; mi++) {
        #pragma unroll
        for (int ni = 0; ni < 4; ni++) {
            int n = bn * 128 + wn * 64 + ni * 16 + l15;
            v4f ac = acc[mi][ni];
            #pragma unroll
            for (int r = 0; r < 4; r++) {
                int m = bm * 128 + wm * 64 + mi * 16 + rbase + r;
                size_t o = (size_t)m * N + n;
                float c = ac[r];
                if (EPI == 0)      Cf[o] = c;
                else if (EPI == 1) Cb[o] = f2bf(c);
                else if (EPI == 2) Cf[o] = softplusf(c + bias[n]);
                else               Cf[o] = c + bias[n] + res[o];
            }
        }
    }
}

// ---------------- 64x64 split-K GEMM with atomic epilogue (x_proj, N=96) ----------------
__global__ __launch_bounds__(256) void gemm_xp(const unsigned short* __restrict__ A,
                                               const unsigned short* __restrict__ B,
                                               int M, int N, int K, int kLen,
                                               float* __restrict__ Cf) {
    __shared__ unsigned short As[64][40];
    __shared__ unsigned short Bs[64][40];
    int tid = threadIdx.x;
    int bm = blockIdx.x, bn = blockIdx.y;
    int k0base = blockIdx.z * kLen;
    int row = tid >> 2, cg = (tid & 3) << 3;
    int lane = tid & 63, w = tid >> 6;
    int wm = w >> 1, wn = w & 1;
    int l15 = lane & 15, kq = (lane >> 4) << 3;

    v4f acc00 = {0.f, 0.f, 0.f, 0.f};
    v4f acc01 = acc00, acc10 = acc00, acc11 = acc00;

    const size_t arow = (size_t)(bm * 64 + row) * K;
    int brow_i = bn * 64 + row;
    const size_t brow = (size_t)brow_i * K;
    bool bok = brow_i < N;

    for (int k0 = k0base; k0 < k0base + kLen; k0 += 32) {
        float4 av = *reinterpret_cast<const float4*>(A + arow + k0 + cg);
        float4 bv = make_float4(0.f, 0.f, 0.f, 0.f);
        if (bok) bv = *reinterpret_cast<const float4*>(B + brow + k0 + cg);
        __syncthreads();
        *reinterpret_cast<float4*>(&As[row][cg]) = av;
        *reinterpret_cast<float4*>(&Bs[row][cg]) = bv;
        __syncthreads();
        v8bf a0 = *reinterpret_cast<const v8bf*>(&As[(wm << 5) + l15][kq]);
        v8bf a1 = *reinterpret_cast<const v8bf*>(&As[(wm << 5) + 16 + l15][kq]);
        v8bf b0 = *reinterpret_cast<const v8bf*>(&Bs[(wn << 5) + l15][kq]);
        v8bf b1 = *reinterpret_cast<const v8bf*>(&Bs[(wn << 5) + 16 + l15][kq]);
        acc00 = __builtin_amdgcn_mfma_f32_16x16x32_bf16(a0, b0, acc00, 0, 0, 0);
        acc01 = __builtin_amdgcn_mfma_f32_16x16x32_bf16(a0, b1, acc01, 0, 0, 0);
        acc10 = __builtin_amdgcn_mfma_f32_16x16x32_bf16(a1, b0, acc10, 0, 0, 0);
        acc11 = __builtin_amdgcn_mfma_f32_16x16x32_bf16(a1, b1, acc11, 0, 0, 0);
    }

    int mbase = bm * 64 + (wm << 5);
    int nbase = bn * 64 + (wn << 5) + l15;
    int rbase = (lane >> 4) << 2;
    v4f accs[4] = {acc00, acc01, acc10, acc11};
    #pragma unroll
    for (int mi = 0; mi < 2; mi++) {
        #pragma unroll
        for (int ni = 0; ni < 2; ni++) {
            int n = nbase + ni * 16;
            if (n >= N) continue;
            v4f ac = accs[mi * 2 + ni];
            #pragma unroll
            for (int r = 0; r < 4; r++) {
                int m = mbase + mi * 16 + rbase + r;
                atomicAdd(&Cf[(size_t)m * N + n], ac[r]);
            }
        }
    }
}

// ---------------- host launch ----------------
extern "C" void kernel_launch(void* const* d_in, const int* in_sizes, int n_in,
                              void* d_out, int out_size, void* d_ws, size_t ws_size,
                              hipStream_t stream) {
    (void)in_sizes; (void)n_in; (void)out_size; (void)ws_size;
    const int TOK = 4096;
    const int DM = 1024, DI = 1024;

    const float* hs       = (const float*)d_in[0];
    const float* ln_g     = (const float*)d_in[1];
    const float* ln_b     = (const float*)d_in[2];
    const float* in_proj  = (const float*)d_in[3];
    const float* conv_w   = (const float*)d_in[4];
    const float* conv_b   = (const float*)d_in[5];
    const float* x_proj   = (const float*)d_in[6];
    const float* dt_proj  = (const float*)d_in[7];
    const float* dt_b     = (const float*)d_in[8];
    const float* A_log    = (const float*)d_in[9];
    const float* Dp       = (const float*)d_in[10];
    const float* conv_w_b = (const float*)d_in[11];
    const float* conv_b_b = (const float*)d_in[12];
    const float* x_proj_b = (const float*)d_in[13];
    const float* dt_proj_b= (const float*)d_in[14];
    const float* dt_b_b   = (const float*)d_in[15];
    const float* A_log_b  = (const float*)d_in[16];
    const float* Dp_b     = (const float*)d_in[17];
    const float* out_proj = (const float*)d_in[18];
    const float* fc_w     = (const float*)d_in[19];
    const float* fc_b     = (const float*)d_in[20];

    uint8_t* p = (uint8_t*)d_ws;
    auto alloc = [&](size_t bytes) -> void* {
        void* r = (void*)p;
        p += (bytes + 255) & ~(size_t)255;
        return r;
    };
    unsigned short* hsb   = (unsigned short*)alloc((size_t)TOK * DM * 2);
    float*          xz    = (float*)alloc((size_t)TOK * 2048 * 4);
    unsigned short* ubf   = (unsigned short*)alloc((size_t)TOK * DI * 2);
    float*          xdbl  = (float*)alloc((size_t)TOK * 96 * 4);
    unsigned short* xdA   = (unsigned short*)alloc((size_t)TOK * 64 * 2);
    float*          delta = (float*)alloc((size_t)TOK * DI * 4);
    float*          hfin  = (float*)alloc((size_t)4 * 1024 * 32 * 16 * 4);
    float*          aprod = (float*)alloc((size_t)4 * 1024 * 32 * 16 * 4);
    float*          hin   = (float*)alloc((size_t)4 * 1024 * 32 * 16 * 4);
    float*          yf    = (float*)alloc((size_t)TOK * DI * 4);
    unsigned short* ybf   = (unsigned short*)alloc((size_t)TOK * DI * 2);
    unsigned short* o1b   = (unsigned short*)alloc((size_t)TOK * DI * 2);
    unsigned short* wip   = (unsigned short*)alloc((size_t)2048 * 1024 * 2);
    unsigned short* wxp   = (unsigned short*)alloc((size_t)96 * 1024 * 2);
    unsigned short* wxpB  = (unsigned short*)alloc((size_t)96 * 1024 * 2);
    unsigned short* wdt   = (unsigned short*)alloc((size_t)1024 * 64 * 2);
    unsigned short* wdtB  = (unsigned short*)alloc((size_t)1024 * 64 * 2);
    unsigned short* wout  = (unsigned short*)alloc((size_t)1024 * 1024 * 2);
    unsigned short* wfc   = (unsigned short*)alloc((size_t)1024 * 1024 * 2);
    float*          AnF   = (float*)alloc((size_t)DI * 16 * 4);
    float*          AnB   = (float*)alloc((size_t)DI * 16 * 4);

    // fused weight casts (sizes all multiples of 1024)
    CastJobs jobs;
    int blk = 0;
    auto addSeg = [&](int i, const float* s, unsigned short* d, int n) {
        jobs.seg[i] = CastSeg{s, d, blk};
        blk += n / 1024;
    };
    addSeg(0, in_proj,   wip,  2048 * 1024);
    addSeg(1, x_proj,    wxp,  96 * 1024);
    addSeg(2, x_proj_b,  wxpB, 96 * 1024);
    addSeg(3, dt_proj,   wdt,  1024 * 64);
    addSeg(4, dt_proj_b, wdtB, 1024 * 64);
    addSeg(5, out_proj,  wout, 1024 * 1024);
    addSeg(6, fc_w,      wfc,  1024 * 1024);
    cast_multi<<<blk, 256, 0, stream>>>(jobs);
    aneg2<<<64, 256, 0, stream>>>(A_log, A_log_b, AnF, AnB);

    ln_kernel<<<TOK, 256, 0, stream>>>(hs, ln_g, ln_b, hsb);

    // xz = hs @ in_proj.T : (4096, 2048)
    gemm128<0><<<dim3(32, 16), 256, 0, stream>>>(hsb, wip, TOK, 2048, 1024,
                                                 nullptr, nullptr, xz, nullptr);
    // ---- forward branch ----
    conv_silu<0><<<16384, 256, 0, stream>>>(xz, conv_w, conv_b, ubf);
    hipMemsetAsync(xdbl, 0, (size_t)TOK * 96 * 4, stream);
    gemm_xp<<<dim3(64, 2, 4), 256, 0, stream>>>(ubf, wxp, TOK, 96, 1024, 256, xdbl);
    cast_xdbl64<<<1024, 256, 0, stream>>>(xdbl, xdA);
    gemm128<2><<<dim3(32, 8), 256, 0, stream>>>(xdA, wdt, TOK, 1024, 64,
                                                dt_b, nullptr, delta, nullptr);
    scan_p1<<<512, 256, 0, stream>>>(delta, ubf, xdbl, AnF, hfin, aprod);
    scan_p2<<<256, 256, 0, stream>>>(hfin, aprod, hin);
    scan_p3<0, 0><<<512, 256, 0, stream>>>(delta, ubf, xdbl, AnF, hin, Dp, xz,
                                           nullptr, yf, nullptr);
    // ---- backward branch ----
    conv_silu<1><<<16384, 256, 0, stream>>>(xz, conv_w_b, conv_b_b, ubf);
    hipMemsetAsync(xdbl, 0, (size_t)TOK * 96 * 4, stream);
    gemm_xp<<<dim3(64, 2, 4), 256, 0, stream>>>(ubf, wxpB, TOK, 96, 1024, 256, xdbl);
    cast_xdbl64<<<1024, 256, 0, stream>>>(xdbl, xdA);
    gemm128<2><<<dim3(32, 8), 256, 0, stream>>>(xdA, wdtB, TOK, 1024, 64,
                                                dt_b_b, nullptr, delta, nullptr);
    scan_p1<<<512, 256, 0, stream>>>(delta, ubf, xdbl, AnB, hfin, aprod);
    scan_p2<<<256, 256, 0, stream>>>(hfin, aprod, hin);
    scan_p3<1, 1><<<512, 256, 0, stream>>>(delta, ubf, xdbl, AnB, hin, Dp_b, xz,
                                           yf, nullptr, ybf);
    // ---- head ----
    gemm128<1><<<dim3(32, 8), 256, 0, stream>>>(ybf, wout, TOK, 1024, 1024,
                                                nullptr, nullptr, nullptr, o1b);
    gemm128<3><<<dim3(32, 8), 256, 0, stream>>>(o1b, wfc, TOK, 1024, 1024,
                                                fc_b, hs, (float*)d_out, nullptr);
}